// Round 9
// baseline (1818.810 us; speedup 1.0000x reference)
//
#include <hip/hip_runtime.h>
#include <cfloat>

// Problem constants
#define B_   4
#define C_   512
#define HW_  4096          // 64*64
#define R_   16384         // B_*HW_ rows of x
#define N_   16384         // memory bank rows
#define ALPHA_ 0.1f
#define SCALE_ ((float)(1000.0/49152.0))

#define NCHUNK 32          // 32 col-chunks of 512 -> 4096 work items (queue-scheduled)
#define NITEMS (128 * NCHUNK)
#define GRID   1024        // >= max residency; surplus blocks drain the queue and exit

typedef unsigned int u32;
typedef unsigned short u16;
typedef unsigned char u8;
typedef __attribute__((ext_vector_type(2))) unsigned long long u64x2;  // 16B = 2 fp8 frags
typedef __attribute__((ext_vector_type(4))) float f32x4;

typedef const __attribute__((address_space(1))) u32* gas_u32;
typedef __attribute__((address_space(3))) u32* las_u32;

__device__ __forceinline__ void async16(const void* g, void* l) {
    __builtin_amdgcn_global_load_lds((gas_u32)g, (las_u32)l, 16, 0, 0);
}

__device__ __forceinline__ u32 pk_fp8x4(float a, float b, float c, float d) {
    u32 v = __builtin_amdgcn_cvt_pk_fp8_f32(a, b, 0, false);   // bytes 0,1
    v = __builtin_amdgcn_cvt_pk_fp8_f32(c, d, v, true);        // bytes 2,3
    return v;
}

__device__ __forceinline__ void ins6(float (&t)[6], float v) {
    if (v < t[5]) {                     // rarely taken
        t[5] = v;
        #pragma unroll
        for (int q = 5; q >= 1; --q) {
            float lo = fminf(t[q-1], t[q]);
            float hi = fmaxf(t[q-1], t[q]);
            t[q-1] = lo; t[q] = hi;
        }
    }
}

// ---------- mem fp32 -> Mb fp8 + m2 (exact fp32 norms) ----------
__global__ void conv_mem_kernel(const float* __restrict__ mem,
                                u8* __restrict__ Mb, float* __restrict__ m2) {
    int w = threadIdx.x >> 6, l = threadIdx.x & 63;
    int row = blockIdx.x * 4 + w;
    const float4* p = (const float4*)(mem + (size_t)row * C_);
    float4 a = p[l], b = p[l + 64];
    float s = a.x*a.x + a.y*a.y + a.z*a.z + a.w*a.w
            + b.x*b.x + b.y*b.y + b.z*b.z + b.w*b.w;
    *(u32*)(Mb + (size_t)row * C_ + l*4)       = pk_fp8x4(a.x, a.y, a.z, a.w);
    *(u32*)(Mb + (size_t)row * C_ + 256 + l*4) = pk_fp8x4(b.x, b.y, b.z, b.w);
    #pragma unroll
    for (int off = 32; off > 0; off >>= 1) s += __shfl_down(s, off);
    if (l == 0) m2[row] = s;
}

// ---------- phi [b][c][n] -> Xb[g][c] fp8 (transpose via LDS) + fused x2 atomics ----------
__global__ void conv_phi_kernel(const float* __restrict__ phi, u8* __restrict__ Xb,
                                float* __restrict__ x2) {
    __shared__ float T[64][65];
    int t = threadIdx.x;
    int n0 = blockIdx.x * 64, c0 = blockIdx.y * 64, b = blockIdx.z;
    const float* src = phi + ((size_t)b * C_ + c0) * HW_ + n0;
    int l = t & 63, cg = t >> 6;
    float sq = 0.f;
    #pragma unroll
    for (int p = 0; p < 16; ++p) {
        int c = cg + p * 4;
        float v = src[(size_t)c * HW_ + l];      // coalesced along n
        T[c][l] = v;
        sq = fmaf(v, v, sq);
    }
    atomicAdd(&x2[(size_t)b * HW_ + n0 + l], sq);
    __syncthreads();
    int cq = t & 15, gl0 = t >> 4;
    #pragma unroll
    for (int p = 0; p < 4; ++p) {
        int gl = gl0 + p * 16;
        u32 v = pk_fp8x4(T[cq*4+0][gl], T[cq*4+1][gl],
                         T[cq*4+2][gl], T[cq*4+3][gl]);
        size_t g = (size_t)b * HW_ + n0 + gl;
        *(u32*)(Xb + g * C_ + c0 + cq*4) = v;
    }
}

// ---------- main: fp8 MFMA GEMM, swapped operands (A=bank, B=x -> top[2][6]),
// XOR-swizzled LDS (verified R5/R7), persistent blocks + atomic work queue.
// launch_bounds(256,3): 170-reg budget -> no scratch spill (R8 failure mode). ----------
__global__ __launch_bounds__(256, 3) void gemm_topk_kernel(
    const u8* __restrict__ Xb, const u8* __restrict__ Mb,
    const float* __restrict__ m2, float* __restrict__ P /* [R][NCHUNK][6] */,
    u32* __restrict__ counter) {
    __shared__ __align__(16) u8 smem[16384];   // Xs(8K) | Ms(8K); merge buf reuses 6.4K
    __shared__ u32 s_item;
    u8* Xs = smem;                       // [x-row 0..127][64 B], 16B-chunks XOR-swizzled
    u8* Ms = smem + 8192;                // [bank-col 0..127][64 B]

    const int t = threadIdx.x;
    const int w = t >> 6, l = t & 63;
    const int rh  = w * 32;             // wave's 32 x-rows (stages rows rh..rh+31 of both)
    const int fm  = l & 15;
    const int rq  = l >> 4;
    // frag read: physical chunk = rq ^ ((fm>>1)&3)  (verified conflict-free, R5/R7)
    const int pc  = (rq ^ ((fm >> 1) & 3)) * 16;
    // staging swizzle (verified R7): phys chunk l&3 of row l>>2 holds logical (l&3)^((l>>3)&3)
    const int srow4 = l >> 2;
    const int soff  = (((l & 3) ^ ((l >> 3) & 3)) * 16);

    for (;;) {
        __syncthreads();                 // protect s_item + smem reuse across items
        if (t == 0) s_item = atomicAdd(counter, 1u);
        __syncthreads();
        const u32 item = s_item;
        if (item >= NITEMS) break;

        const int g0  = (int)(item >> 5) * 128;          // row-tile
        const int n0c = (int)(item & (NCHUNK - 1)) * (N_ / NCHUNK);  // col-chunk (512)

        const u8* Xsrc = Xb + (size_t)(g0 + rh) * C_;
        u8* XsW = Xs + rh * 64;          // wave-uniform staging base
        u8* MsW = Ms + rh * 64;

        float top[2][6];                 // slot m: x-row = g0 + rh + m*16 + fm
        #pragma unroll
        for (int m = 0; m < 2; ++m)
            #pragma unroll
            for (int q = 0; q < 6; ++q) top[m][q] = FLT_MAX;

        for (int nt = 0; nt < N_ / NCHUNK / 128; ++nt) {
            const int n0 = n0c + nt * 128;
            const u8* Msrc = Mb + (size_t)(n0 + rh) * C_;

            f32x4 acc[2][8];             // acc[m][a]: C-row = bank-col a*16+rq*4+j
            #pragma unroll
            for (int m = 0; m < 2; ++m)
                #pragma unroll
                for (int a = 0; a < 8; ++a) acc[m][a] = (f32x4)0.f;

            for (int s = 0; s < 8; ++s) {
                const int k0 = s * 64;
                #pragma unroll
                for (int i = 0; i < 2; ++i) {
                    async16(Xsrc + (size_t)(i*16 + srow4) * C_ + k0 + soff, XsW + i*1024);
                    async16(Msrc + (size_t)(i*16 + srow4) * C_ + k0 + soff, MsW + i*1024);
                }
                __syncthreads();
                u64x2 xv[2];             // B operand: x fragments
                #pragma unroll
                for (int m = 0; m < 2; ++m)
                    xv[m] = *(const u64x2*)(Xs + (rh + m*16 + fm) * 64 + pc);
                #pragma unroll
                for (int a = 0; a < 8; ++a) {
                    u64x2 av = *(const u64x2*)(Ms + (a*16 + fm) * 64 + pc);  // A: bank
                    #pragma unroll
                    for (int m = 0; m < 2; ++m) {
                        acc[m][a] = __builtin_amdgcn_mfma_f32_16x16x32_fp8_fp8(
                            (long)av.x, (long)xv[m].x, acc[m][a], 0, 0, 0);
                        acc[m][a] = __builtin_amdgcn_mfma_f32_16x16x32_fp8_fp8(
                            (long)av.y, (long)xv[m].y, acc[m][a], 0, 0, 0);
                    }
                }
                __syncthreads();
            }

            // epilogue: score = m2[c] - 2*dot; c = n0 + a*16 + rq*4 + j
            float vm0 = FLT_MAX, vm1 = FLT_MAX;
            #pragma unroll 2
            for (int a = 0; a < 8; ++a) {
                float4 q = *(const float4*)(m2 + n0 + a * 16 + rq * 4);  // L1-resident
                f32x4 a0 = acc[0][a], a1 = acc[1][a];
                vm0 = fminf(vm0, fminf(fminf(q.x - 2.f*a0.x, q.y - 2.f*a0.y),
                                       fminf(q.z - 2.f*a0.z, q.w - 2.f*a0.w)));
                vm1 = fminf(vm1, fminf(fminf(q.x - 2.f*a1.x, q.y - 2.f*a1.y),
                                       fminf(q.z - 2.f*a1.z, q.w - 2.f*a1.w)));
            }
            if (vm0 < top[0][5]) {       // rare slow path: recompute + insert
                #pragma unroll 2
                for (int a = 0; a < 8; ++a) {
                    float4 q = *(const float4*)(m2 + n0 + a * 16 + rq * 4);
                    f32x4 a0 = acc[0][a];
                    ins6(top[0], q.x - 2.f*a0.x); ins6(top[0], q.y - 2.f*a0.y);
                    ins6(top[0], q.z - 2.f*a0.z); ins6(top[0], q.w - 2.f*a0.w);
                }
            }
            if (vm1 < top[1][5]) {
                #pragma unroll 2
                for (int a = 0; a < 8; ++a) {
                    float4 q = *(const float4*)(m2 + n0 + a * 16 + rq * 4);
                    f32x4 a1 = acc[1][a];
                    ins6(top[1], q.x - 2.f*a1.x); ins6(top[1], q.y - 2.f*a1.y);
                    ins6(top[1], q.z - 2.f*a1.z); ins6(top[1], q.w - 2.f*a1.w);
                }
            }
        }

        // merge: per x-row, combine 4 rq-lanes' top-6 -> per-chunk top-6 partial.
        float* Mg = (float*)smem;        // 64*25 floats = 6400 B (reuses Xs region)
        #pragma unroll 1
        for (int p = 0; p < 2; ++p) {
            __syncthreads();
            if ((w >> 1) == p) {
                #pragma unroll
                for (int m = 0; m < 2; ++m) {
                    int lrow = (w & 1) * 32 + m * 16 + fm;
                    #pragma unroll
                    for (int q = 0; q < 6; ++q)
                        Mg[lrow * 25 + rq * 6 + q] = top[m][q];
                }
            }
            __syncthreads();
            if (t < 64) {
                float t6[6];
                #pragma unroll
                for (int q = 0; q < 6; ++q) t6[q] = FLT_MAX;
                const float* row = Mg + t * 25;
                #pragma unroll
                for (int v = 0; v < 24; ++v) ins6(t6, row[v]);
                float* dst = P + ((size_t)(g0 + p * 64 + t) * NCHUNK + (item & (NCHUNK-1))) * 6;
                #pragma unroll
                for (int q = 0; q < 6; ++q) dst[q] = t6[q];
            }
        }
    }
}

// ---------- merge chunks + hinge loss ----------
__global__ void finalize_kernel(const float* __restrict__ P, const float* __restrict__ x2,
                                const float* __restrict__ rp, float* __restrict__ out) {
    int g = blockIdx.x * 256 + threadIdx.x;
    float t6[6];
    #pragma unroll
    for (int q = 0; q < 6; ++q) t6[q] = FLT_MAX;
    const f32x4* pp = (const f32x4*)(P + (size_t)g * (NCHUNK * 6));
    #pragma unroll 4
    for (int q = 0; q < NCHUNK * 6 / 4; ++q) {
        f32x4 v = pp[q];
        ins6(t6, v.x); ins6(t6, v.y); ins6(t6, v.z); ins6(t6, v.w);
    }
    float x2g = x2[g];
    float rv = rp[0], r2 = rv * rv;
    float s = 0.f;
    #pragma unroll
    for (int i = 0; i < 3; ++i) {
        float d = fmaxf(t6[i] + x2g, 0.f);
        s += fmaxf(d - r2, 0.f);
    }
    #pragma unroll
    for (int i = 3; i < 6; ++i) {
        float d = fmaxf(t6[i] + x2g, 0.f);
        s += fmaxf(r2 - d - ALPHA_, 0.f);
    }
    #pragma unroll
    for (int off = 32; off > 0; off >>= 1) s += __shfl_down(s, off);
    __shared__ float red[4];
    int w = threadIdx.x >> 6, l = threadIdx.x & 63;
    if (l == 0) red[w] = s;
    __syncthreads();
    if (threadIdx.x == 0)
        atomicAdd(out, (red[0] + red[1] + red[2] + red[3]) * SCALE_);
}

// ================= Round-1 fp32 fallback (used only if ws too small) =================
#define TM 64
#define TN 64
#define KC 64
#define LDP 68

__global__ void m2_kernel(const float* __restrict__ mem, float* __restrict__ m2) {
    int wave = threadIdx.x >> 6, lane = threadIdx.x & 63;
    int row = blockIdx.x * 4 + wave;
    const float4* p = reinterpret_cast<const float4*>(mem + (size_t)row * C_);
    float4 a = p[lane], b = p[lane + 64];
    float s = a.x*a.x + a.y*a.y + a.z*a.z + a.w*a.w
            + b.x*b.x + b.y*b.y + b.z*b.z + b.w*b.w;
    #pragma unroll
    for (int off = 32; off > 0; off >>= 1) s += __shfl_down(s, off);
    if (lane == 0) m2[row] = s;
}

__global__ void x2f_kernel(const float* __restrict__ phi, float* __restrict__ x2) {
    int g = blockIdx.x * blockDim.x + threadIdx.x;
    int b = g >> 12;
    int n = g & 4095;
    const float* p = phi + (size_t)b * C_ * HW_ + n;
    float s = 0.f;
    #pragma unroll 8
    for (int c = 0; c < C_; ++c) {
        float v = p[(size_t)c * HW_];
        s = fmaf(v, v, s);
    }
    x2[g] = s;
}

__global__ __launch_bounds__(256) void dist_loss_kernel(
    const float* __restrict__ phi, const float* __restrict__ mem,
    const float* __restrict__ rp,  const float* __restrict__ m2,
    const float* __restrict__ x2,  float* __restrict__ out) {
    __shared__ float smem[2 * TM * LDP];
    float* xs = smem;
    float* ms = smem + TM * LDP;
    const int tid = threadIdx.x;
    const int tx = tid & 15, ty = tid >> 4;
    const int g0 = blockIdx.x * TM;
    const int b = g0 >> 12, n0img = g0 & 4095;
    const float* phiB = phi + (size_t)b * C_ * HW_ + n0img;
    float top[4][6];
    #pragma unroll
    for (int i = 0; i < 4; ++i)
        #pragma unroll
        for (int q = 0; q < 6; ++q) top[i][q] = FLT_MAX;
    float x2v[4];
    #pragma unroll
    for (int i = 0; i < 4; ++i) x2v[i] = x2[g0 + ty * 4 + i];
    for (int nt = 0; nt < N_ / TN; ++nt) {
        const int n0 = nt * TN;
        float acc[4][4];
        #pragma unroll
        for (int i = 0; i < 4; ++i)
            #pragma unroll
            for (int j = 0; j < 4; ++j) acc[i][j] = 0.f;
        for (int s = 0; s < C_ / KC; ++s) {
            const int k0 = s * KC;
            {
                int rr = tid & 63, cb = tid >> 6;
                #pragma unroll
                for (int p = 0; p < 16; ++p) {
                    int cc = p * 4 + cb;
                    xs[rr * LDP + cc] = phiB[(size_t)(k0 + cc) * HW_ + rr];
                }
            }
            {
                int kq = tid & 15, cb = tid >> 4;
                #pragma unroll
                for (int p = 0; p < 4; ++p) {
                    int c = p * 16 + cb;
                    float4 v = *reinterpret_cast<const float4*>(
                        mem + (size_t)(n0 + c) * C_ + k0 + kq * 4);
                    ms[(kq*4+0)*LDP + c] = v.x; ms[(kq*4+1)*LDP + c] = v.y;
                    ms[(kq*4+2)*LDP + c] = v.z; ms[(kq*4+3)*LDP + c] = v.w;
                }
            }
            __syncthreads();
            #pragma unroll
            for (int kq = 0; kq < KC / 4; ++kq) {
                float4 xa[4], mb[4];
                #pragma unroll
                for (int i = 0; i < 4; ++i)
                    xa[i] = *reinterpret_cast<const float4*>(&xs[(ty*4+i)*LDP + kq*4]);
                #pragma unroll
                for (int kk = 0; kk < 4; ++kk)
                    mb[kk] = *reinterpret_cast<const float4*>(&ms[(kq*4+kk)*LDP + tx*4]);
                #pragma unroll
                for (int i = 0; i < 4; ++i) {
                    const float xk[4] = {xa[i].x, xa[i].y, xa[i].z, xa[i].w};
                    #pragma unroll
                    for (int kk = 0; kk < 4; ++kk) {
                        const float mc[4] = {mb[kk].x, mb[kk].y, mb[kk].z, mb[kk].w};
                        #pragma unroll
                        for (int j = 0; j < 4; ++j)
                            acc[i][j] = fmaf(xk[kk], mc[j], acc[i][j]);
                    }
                }
            }
            __syncthreads();
        }
        #pragma unroll
        for (int j = 0; j < 4; ++j) {
            float m2v = m2[n0 + tx * 4 + j];
            #pragma unroll
            for (int i = 0; i < 4; ++i) {
                float d = fmaxf(x2v[i] + m2v - 2.f * acc[i][j], 0.f);
                ins6(top[i], d);
            }
        }
    }
    __syncthreads();
    float* mg = smem;
    #pragma unroll
    for (int i = 0; i < 4; ++i)
        #pragma unroll
        for (int q = 0; q < 6; ++q)
            mg[(ty*4+i)*97 + tx*6 + q] = top[i][q];
    __syncthreads();
    if (tid < 64) {
        float t6[6];
        #pragma unroll
        for (int q = 0; q < 6; ++q) t6[q] = FLT_MAX;
        const float* row = mg + tid * 97;
        for (int v = 0; v < 96; ++v) ins6(t6, row[v]);
        float rv = rp[0], r2 = rv * rv;
        float s = fmaxf(t6[0]-r2,0.f) + fmaxf(t6[1]-r2,0.f) + fmaxf(t6[2]-r2,0.f)
                + fmaxf(r2-t6[3]-ALPHA_,0.f) + fmaxf(r2-t6[4]-ALPHA_,0.f)
                + fmaxf(r2-t6[5]-ALPHA_,0.f);
        #pragma unroll
        for (int off = 32; off > 0; off >>= 1) s += __shfl_down(s, off);
        if (tid == 0) atomicAdd(out, s * SCALE_);
    }
}

extern "C" void kernel_launch(void* const* d_in, const int* in_sizes, int n_in,
                              void* d_out, int out_size, void* d_ws, size_t ws_size,
                              hipStream_t stream) {
    const float* phi = (const float*)d_in[0];
    const float* mem = (const float*)d_in[1];
    const float* rp  = (const float*)d_in[2];
    float* out = (float*)d_out;

    const size_t offX  = 0;
    const size_t offM  = (size_t)R_ * C_;                // Xb fp8: 8 MB
    const size_t offx2 = offM + (size_t)N_ * C_;         // Mb fp8: 8 MB
    const size_t offm2 = offx2 + (size_t)R_ * 4;
    const size_t offP  = offm2 + (size_t)N_ * 4;
    const size_t offC  = offP + (size_t)R_ * NCHUNK * 6 * 4;   // P: ~12.6 MB
    const size_t need  = offC + 64;                      // ~28.8 MB

    hipMemsetAsync(out, 0, sizeof(float), stream);

    if (ws_size >= need) {
        u8*    Xb = (u8*)((char*)d_ws + offX);
        u8*    Mb = (u8*)((char*)d_ws + offM);
        float* x2 = (float*)((char*)d_ws + offx2);
        float* m2 = (float*)((char*)d_ws + offm2);
        float* P  = (float*)((char*)d_ws + offP);
        u32*   cnt = (u32*)((char*)d_ws + offC);

        hipMemsetAsync(x2, 0, (size_t)R_ * 4, stream);   // x2 accumulated atomically
        hipMemsetAsync(cnt, 0, sizeof(u32), stream);     // work-queue counter
        conv_mem_kernel<<<N_ / 4, 256, 0, stream>>>(mem, Mb, m2);
        conv_phi_kernel<<<dim3(HW_ / 64, C_ / 64, B_), 256, 0, stream>>>(phi, Xb, x2);
        gemm_topk_kernel<<<GRID, 256, 0, stream>>>(Xb, Mb, m2, P, cnt);
        finalize_kernel<<<R_ / 256, 256, 0, stream>>>(P, x2, rp, out);
    } else {
        // fp32 fallback (verified round 1)
        float* m2 = (float*)d_ws;
        float* x2 = m2 + N_;
        m2_kernel<<<N_ / 4, 256, 0, stream>>>(mem, m2);
        x2f_kernel<<<R_ / 256, 256, 0, stream>>>(phi, x2);
        dist_loss_kernel<<<R_ / TM, 256, 0, stream>>>(phi, mem, rp, m2, x2, out);
    }
}

// Round 10
// 383.059 us; speedup vs baseline: 4.7481x; 4.7481x over previous
//
#include <hip/hip_runtime.h>
#include <cfloat>

// Problem constants
#define B_   4
#define C_   512
#define HW_  4096          // 64*64
#define R_   16384         // B_*HW_ rows of x
#define N_   16384         // memory bank rows
#define ALPHA_ 0.1f
#define SCALE_ ((float)(1000.0/49152.0))

#define NCHUNK 4           // R7 config (verified best)

typedef unsigned int u32;
typedef unsigned short u16;
typedef unsigned char u8;
typedef __attribute__((ext_vector_type(2))) unsigned long long u64x2;  // 16B = 2 fp8 frags
typedef __attribute__((ext_vector_type(4))) float f32x4;

typedef const __attribute__((address_space(1))) u32* gas_u32;
typedef __attribute__((address_space(3))) u32* las_u32;

__device__ __forceinline__ void async16(const void* g, void* l) {
    __builtin_amdgcn_global_load_lds((gas_u32)g, (las_u32)l, 16, 0, 0);
}

__device__ __forceinline__ u32 pk_fp8x4(float a, float b, float c, float d) {
    u32 v = __builtin_amdgcn_cvt_pk_fp8_f32(a, b, 0, false);   // bytes 0,1
    v = __builtin_amdgcn_cvt_pk_fp8_f32(c, d, v, true);        // bytes 2,3
    return v;
}

__device__ __forceinline__ void ins6(float (&t)[6], float v) {
    if (v < t[5]) {                     // rarely taken
        t[5] = v;
        #pragma unroll
        for (int q = 5; q >= 1; --q) {
            float lo = fminf(t[q-1], t[q]);
            float hi = fmaxf(t[q-1], t[q]);
            t[q-1] = lo; t[q] = hi;
        }
    }
}

// ---------- mem fp32 -> Mb fp8 + m2 (exact fp32 norms) ----------
__global__ void conv_mem_kernel(const float* __restrict__ mem,
                                u8* __restrict__ Mb, float* __restrict__ m2) {
    int w = threadIdx.x >> 6, l = threadIdx.x & 63;
    int row = blockIdx.x * 4 + w;
    const float4* p = (const float4*)(mem + (size_t)row * C_);
    float4 a = p[l], b = p[l + 64];
    float s = a.x*a.x + a.y*a.y + a.z*a.z + a.w*a.w
            + b.x*b.x + b.y*b.y + b.z*b.z + b.w*b.w;
    *(u32*)(Mb + (size_t)row * C_ + l*4)       = pk_fp8x4(a.x, a.y, a.z, a.w);
    *(u32*)(Mb + (size_t)row * C_ + 256 + l*4) = pk_fp8x4(b.x, b.y, b.z, b.w);
    #pragma unroll
    for (int off = 32; off > 0; off >>= 1) s += __shfl_down(s, off);
    if (l == 0) m2[row] = s;
}

// ---------- phi [b][c][n] -> Xb[g][c] fp8 (transpose via LDS) + fused x2 atomics ----------
__global__ void conv_phi_kernel(const float* __restrict__ phi, u8* __restrict__ Xb,
                                float* __restrict__ x2) {
    __shared__ float T[64][65];
    int t = threadIdx.x;
    int n0 = blockIdx.x * 64, c0 = blockIdx.y * 64, b = blockIdx.z;
    const float* src = phi + ((size_t)b * C_ + c0) * HW_ + n0;
    int l = t & 63, cg = t >> 6;
    float sq = 0.f;
    #pragma unroll
    for (int p = 0; p < 16; ++p) {
        int c = cg + p * 4;
        float v = src[(size_t)c * HW_ + l];      // coalesced along n
        T[c][l] = v;
        sq = fmaf(v, v, sq);
    }
    atomicAdd(&x2[(size_t)b * HW_ + n0 + l], sq);
    __syncthreads();
    int cq = t & 15, gl0 = t >> 4;
    #pragma unroll
    for (int p = 0; p < 4; ++p) {
        int gl = gl0 + p * 16;
        u32 v = pk_fp8x4(T[cq*4+0][gl], T[cq*4+1][gl],
                         T[cq*4+2][gl], T[cq*4+3][gl]);
        size_t g = (size_t)b * HW_ + n0 + gl;
        *(u32*)(Xb + g * C_ + c0 + cq*4) = v;
    }
}

// ---------- main: fp8 MFMA GEMM = R7 (verified 332 us) + K=128 stages.
// Each stage holds TWO verified 64-B half-tiles (h=0,1) per operand -> barrier
// count per nt halves (16 -> 8); staging swizzle + frag-read pattern are
// byte-identical to R7 within each half. launch_bounds(256,2): no spill (R8/R9). ----------
__global__ __launch_bounds__(256, 2) void gemm_topk_kernel(
    const u8* __restrict__ Xb, const u8* __restrict__ Mb,
    const float* __restrict__ m2, float* __restrict__ P /* [R][NCHUNK][6] */) {
    __shared__ __align__(16) u8 smem[32768];   // Xs(16K: 2 halves) | Ms(16K); merge reuses 24.25K
    u8* Xs = smem;                       // half h at +h*8192: [row 0..127][64 B] swizzled
    u8* Ms = smem + 16384;               // same layout

    const int t = threadIdx.x;
    const int w = t >> 6, l = t & 63;
    const int g0  = blockIdx.x * 128;
    const int n0c = blockIdx.y * (N_ / NCHUNK);
    const int rh  = w * 32;             // wave's 32-row band
    const int fm  = l & 15;
    const int rq  = l >> 4;
    // frag read: physical chunk = rq ^ ((fm>>1)&3)  (verified conflict-free, R5/R7)
    const int pc  = (rq ^ ((fm >> 1) & 3)) * 16;
    // staging swizzle (verified R7): phys chunk l&3 of row l>>2 holds logical (l&3)^((l>>3)&3)
    const int srow4 = l >> 2;
    const int soff  = (((l & 3) ^ ((l >> 3) & 3)) * 16);

    float top[8][6];                     // row-slot = rh + m*16 + rq*4 + j
    #pragma unroll
    for (int s8 = 0; s8 < 8; ++s8)
        #pragma unroll
        for (int q = 0; q < 6; ++q) top[s8][q] = FLT_MAX;

    const u8* Xsrc = Xb + (size_t)(g0 + rh) * C_;
    u8* XsW = Xs + rh * 64;             // wave-uniform staging base (within a half)
    u8* MsW = Ms + rh * 64;

    for (int nt = 0; nt < N_ / NCHUNK / 128; ++nt) {
        const int n0 = n0c + nt * 128;
        const u8* Msrc = Mb + (size_t)(n0 + rh) * C_;

        float m2w[8];
        #pragma unroll
        for (int n = 0; n < 8; ++n) m2w[n] = m2[n0 + n * 16 + fm];

        f32x4 acc[2][8];
        #pragma unroll
        for (int m = 0; m < 2; ++m)
            #pragma unroll
            for (int n = 0; n < 8; ++n) acc[m][n] = (f32x4)0.f;

        for (int s = 0; s < 4; ++s) {    // K=128 per stage (two 64-B halves)
            const int k0 = s * 128;
            #pragma unroll
            for (int h = 0; h < 2; ++h)
                #pragma unroll
                for (int i = 0; i < 2; ++i) {
                    async16(Xsrc + (size_t)(i*16 + srow4) * C_ + k0 + h*64 + soff,
                            XsW + h*8192 + i*1024);
                    async16(Msrc + (size_t)(i*16 + srow4) * C_ + k0 + h*64 + soff,
                            MsW + h*8192 + i*1024);
                }
            __syncthreads();
            #pragma unroll
            for (int h = 0; h < 2; ++h) {
                const u8* Xh = Xs + h * 8192;
                const u8* Mh = Ms + h * 8192;
                u64x2 av[2], bv[8];
                #pragma unroll
                for (int m = 0; m < 2; ++m)
                    av[m] = *(const u64x2*)(Xh + (rh + m*16 + fm) * 64 + pc);
                #pragma unroll
                for (int n = 0; n < 8; ++n)
                    bv[n] = *(const u64x2*)(Mh + (n*16 + fm) * 64 + pc);
                // kf0 = low 8B, kf1 = high 8B: K-permutation applied identically
                // to A and B -> same dot product (verified R7).
                #pragma unroll
                for (int m = 0; m < 2; ++m)
                    #pragma unroll
                    for (int n = 0; n < 8; ++n)
                        acc[m][n] = __builtin_amdgcn_mfma_f32_16x16x32_fp8_fp8(
                            (long)av[m].x, (long)bv[n].x, acc[m][n], 0, 0, 0);
                #pragma unroll
                for (int m = 0; m < 2; ++m)
                    #pragma unroll
                    for (int n = 0; n < 8; ++n)
                        acc[m][n] = __builtin_amdgcn_mfma_f32_16x16x32_fp8_fp8(
                            (long)av[m].y, (long)bv[n].y, acc[m][n], 0, 0, 0);
            }
            __syncthreads();
        }

        // register epilogue: score = m2[c] - 2*dot (x2 added in finalize; monotone/row)
        #pragma unroll
        for (int m = 0; m < 2; ++m)
            #pragma unroll
            for (int j = 0; j < 4; ++j) {
                float d0 = m2w[0] - 2.f * acc[m][0][j];
                float d1 = m2w[1] - 2.f * acc[m][1][j];
                float d2 = m2w[2] - 2.f * acc[m][2][j];
                float d3 = m2w[3] - 2.f * acc[m][3][j];
                float d4 = m2w[4] - 2.f * acc[m][4][j];
                float d5 = m2w[5] - 2.f * acc[m][5][j];
                float d6 = m2w[6] - 2.f * acc[m][6][j];
                float d7 = m2w[7] - 2.f * acc[m][7][j];
                float vmin = fminf(fminf(fminf(d0, d1), fminf(d2, d3)),
                                   fminf(fminf(d4, d5), fminf(d6, d7)));
                float (&tt)[6] = top[m * 4 + j];
                if (vmin < tt[5]) {      // slow path: rare after first tiles
                    ins6(tt, d0); ins6(tt, d1); ins6(tt, d2); ins6(tt, d3);
                    ins6(tt, d4); ins6(tt, d5); ins6(tt, d6); ins6(tt, d7);
                }
            }
    }

    // final merge: per row, combine 16 fm-lanes' top-6 -> per-chunk top-6 partial.
    // Two passes of 64 rows through reused LDS (stride 97 -> conflict-free reads).
    float* Mg = (float*)smem;            // 64*97 = 6208 floats = 24832 B <= 32768
    #pragma unroll 1
    for (int p = 0; p < 2; ++p) {
        __syncthreads();
        if ((w >> 1) == p) {
            #pragma unroll
            for (int m = 0; m < 2; ++m)
                #pragma unroll
                for (int j = 0; j < 4; ++j) {
                    int lrow = (w & 1) * 32 + m * 16 + rq * 4 + j;
                    #pragma unroll
                    for (int q = 0; q < 6; ++q)
                        Mg[lrow * 97 + fm * 6 + q] = top[m * 4 + j][q];
                }
        }
        __syncthreads();
        if (t < 64) {
            float t6[6];
            #pragma unroll
            for (int q = 0; q < 6; ++q) t6[q] = FLT_MAX;
            const float* row = Mg + t * 97;
            for (int v = 0; v < 96; ++v) ins6(t6, row[v]);
            float* dst = P + ((size_t)(g0 + p * 64 + t) * NCHUNK + blockIdx.y) * 6;
            #pragma unroll
            for (int q = 0; q < 6; ++q) dst[q] = t6[q];
        }
    }
}

// ---------- merge chunks + hinge loss ----------
__global__ void finalize_kernel(const float* __restrict__ P, const float* __restrict__ x2,
                                const float* __restrict__ rp, float* __restrict__ out) {
    int g = blockIdx.x * 256 + threadIdx.x;
    float t6[6];
    #pragma unroll
    for (int q = 0; q < 6; ++q) t6[q] = FLT_MAX;
    const f32x4* pp = (const f32x4*)(P + (size_t)g * (NCHUNK * 6));
    #pragma unroll
    for (int q = 0; q < NCHUNK * 6 / 4; ++q) {
        f32x4 v = pp[q];
        ins6(t6, v.x); ins6(t6, v.y); ins6(t6, v.z); ins6(t6, v.w);
    }
    float x2g = x2[g];
    float rv = rp[0], r2 = rv * rv;
    float s = 0.f;
    #pragma unroll
    for (int i = 0; i < 3; ++i) {
        float d = fmaxf(t6[i] + x2g, 0.f);
        s += fmaxf(d - r2, 0.f);
    }
    #pragma unroll
    for (int i = 3; i < 6; ++i) {
        float d = fmaxf(t6[i] + x2g, 0.f);
        s += fmaxf(r2 - d - ALPHA_, 0.f);
    }
    #pragma unroll
    for (int off = 32; off > 0; off >>= 1) s += __shfl_down(s, off);
    __shared__ float red[4];
    int w = threadIdx.x >> 6, l = threadIdx.x & 63;
    if (l == 0) red[w] = s;
    __syncthreads();
    if (threadIdx.x == 0)
        atomicAdd(out, (red[0] + red[1] + red[2] + red[3]) * SCALE_);
}

// ================= Round-1 fp32 fallback (used only if ws too small) =================
#define TM 64
#define TN 64
#define KC 64
#define LDP 68

__global__ void m2_kernel(const float* __restrict__ mem, float* __restrict__ m2) {
    int wave = threadIdx.x >> 6, lane = threadIdx.x & 63;
    int row = blockIdx.x * 4 + wave;
    const float4* p = reinterpret_cast<const float4*>(mem + (size_t)row * C_);
    float4 a = p[lane], b = p[lane + 64];
    float s = a.x*a.x + a.y*a.y + a.z*a.z + a.w*a.w
            + b.x*b.x + b.y*b.y + b.z*b.z + b.w*b.w;
    #pragma unroll
    for (int off = 32; off > 0; off >>= 1) s += __shfl_down(s, off);
    if (lane == 0) m2[row] = s;
}

__global__ void x2f_kernel(const float* __restrict__ phi, float* __restrict__ x2) {
    int g = blockIdx.x * blockDim.x + threadIdx.x;
    int b = g >> 12;
    int n = g & 4095;
    const float* p = phi + (size_t)b * C_ * HW_ + n;
    float s = 0.f;
    #pragma unroll 8
    for (int c = 0; c < C_; ++c) {
        float v = p[(size_t)c * HW_];
        s = fmaf(v, v, s);
    }
    x2[g] = s;
}

__global__ __launch_bounds__(256) void dist_loss_kernel(
    const float* __restrict__ phi, const float* __restrict__ mem,
    const float* __restrict__ rp,  const float* __restrict__ m2,
    const float* __restrict__ x2,  float* __restrict__ out) {
    __shared__ float smem[2 * TM * LDP];
    float* xs = smem;
    float* ms = smem + TM * LDP;
    const int tid = threadIdx.x;
    const int tx = tid & 15, ty = tid >> 4;
    const int g0 = blockIdx.x * TM;
    const int b = g0 >> 12, n0img = g0 & 4095;
    const float* phiB = phi + (size_t)b * C_ * HW_ + n0img;
    float top[4][6];
    #pragma unroll
    for (int i = 0; i < 4; ++i)
        #pragma unroll
        for (int q = 0; q < 6; ++q) top[i][q] = FLT_MAX;
    float x2v[4];
    #pragma unroll
    for (int i = 0; i < 4; ++i) x2v[i] = x2[g0 + ty * 4 + i];
    for (int nt = 0; nt < N_ / TN; ++nt) {
        const int n0 = nt * TN;
        float acc[4][4];
        #pragma unroll
        for (int i = 0; i < 4; ++i)
            #pragma unroll
            for (int j = 0; j < 4; ++j) acc[i][j] = 0.f;
        for (int s = 0; s < C_ / KC; ++s) {
            const int k0 = s * KC;
            {
                int rr = tid & 63, cb = tid >> 6;
                #pragma unroll
                for (int p = 0; p < 16; ++p) {
                    int cc = p * 4 + cb;
                    xs[rr * LDP + cc] = phiB[(size_t)(k0 + cc) * HW_ + rr];
                }
            }
            {
                int kq = tid & 15, cb = tid >> 4;
                #pragma unroll
                for (int p = 0; p < 4; ++p) {
                    int c = p * 16 + cb;
                    float4 v = *reinterpret_cast<const float4*>(
                        mem + (size_t)(n0 + c) * C_ + k0 + kq * 4);
                    ms[(kq*4+0)*LDP + c] = v.x; ms[(kq*4+1)*LDP + c] = v.y;
                    ms[(kq*4+2)*LDP + c] = v.z; ms[(kq*4+3)*LDP + c] = v.w;
                }
            }
            __syncthreads();
            #pragma unroll
            for (int kq = 0; kq < KC / 4; ++kq) {
                float4 xa[4], mb[4];
                #pragma unroll
                for (int i = 0; i < 4; ++i)
                    xa[i] = *reinterpret_cast<const float4*>(&xs[(ty*4+i)*LDP + kq*4]);
                #pragma unroll
                for (int kk = 0; kk < 4; ++kk)
                    mb[kk] = *reinterpret_cast<const float4*>(&ms[(kq*4+kk)*LDP + tx*4]);
                #pragma unroll
                for (int i = 0; i < 4; ++i) {
                    const float xk[4] = {xa[i].x, xa[i].y, xa[i].z, xa[i].w};
                    #pragma unroll
                    for (int kk = 0; kk < 4; ++kk) {
                        const float mc[4] = {mb[kk].x, mb[kk].y, mb[kk].z, mb[kk].w};
                        #pragma unroll
                        for (int j = 0; j < 4; ++j)
                            acc[i][j] = fmaf(xk[kk], mc[j], acc[i][j]);
                    }
                }
            }
            __syncthreads();
        }
        #pragma unroll
        for (int j = 0; j < 4; ++j) {
            float m2v = m2[n0 + tx * 4 + j];
            #pragma unroll
            for (int i = 0; i < 4; ++i) {
                float d = fmaxf(x2v[i] + m2v - 2.f * acc[i][j], 0.f);
                ins6(top[i], d);
            }
        }
    }
    __syncthreads();
    float* mg = smem;
    #pragma unroll
    for (int i = 0; i < 4; ++i)
        #pragma unroll
        for (int q = 0; q < 6; ++q)
            mg[(ty*4+i)*97 + tx*6 + q] = top[i][q];
    __syncthreads();
    if (tid < 64) {
        float t6[6];
        #pragma unroll
        for (int q = 0; q < 6; ++q) t6[q] = FLT_MAX;
        const float* row = mg + tid * 97;
        for (int v = 0; v < 96; ++v) ins6(t6, row[v]);
        float rv = rp[0], r2 = rv * rv;
        float s = fmaxf(t6[0]-r2,0.f) + fmaxf(t6[1]-r2,0.f) + fmaxf(t6[2]-r2,0.f)
                + fmaxf(r2-t6[3]-ALPHA_,0.f) + fmaxf(r2-t6[4]-ALPHA_,0.f)
                + fmaxf(r2-t6[5]-ALPHA_,0.f);
        #pragma unroll
        for (int off = 32; off > 0; off >>= 1) s += __shfl_down(s, off);
        if (tid == 0) atomicAdd(out, s * SCALE_);
    }
}

extern "C" void kernel_launch(void* const* d_in, const int* in_sizes, int n_in,
                              void* d_out, int out_size, void* d_ws, size_t ws_size,
                              hipStream_t stream) {
    const float* phi = (const float*)d_in[0];
    const float* mem = (const float*)d_in[1];
    const float* rp  = (const float*)d_in[2];
    float* out = (float*)d_out;

    const size_t offX  = 0;
    const size_t offM  = (size_t)R_ * C_;                // Xb fp8: 8 MB
    const size_t offx2 = offM + (size_t)N_ * C_;         // Mb fp8: 8 MB
    const size_t offm2 = offx2 + (size_t)R_ * 4;
    const size_t offP  = offm2 + (size_t)N_ * 4;
    const size_t need  = offP + (size_t)R_ * NCHUNK * 6 * 4;  // ~17.8 MB

    hipMemsetAsync(out, 0, sizeof(float), stream);

    if (ws_size >= need) {
        u8*    Xb = (u8*)((char*)d_ws + offX);
        u8*    Mb = (u8*)((char*)d_ws + offM);
        float* x2 = (float*)((char*)d_ws + offx2);
        float* m2 = (float*)((char*)d_ws + offm2);
        float* P  = (float*)((char*)d_ws + offP);

        hipMemsetAsync(x2, 0, (size_t)R_ * 4, stream);   // x2 accumulated atomically
        conv_mem_kernel<<<N_ / 4, 256, 0, stream>>>(mem, Mb, m2);
        conv_phi_kernel<<<dim3(HW_ / 64, C_ / 64, B_), 256, 0, stream>>>(phi, Xb, x2);
        gemm_topk_kernel<<<dim3(128, NCHUNK), 256, 0, stream>>>(Xb, Mb, m2, P);
        finalize_kernel<<<R_ / 256, 256, 0, stream>>>(P, x2, rp, out);
    } else {
        // fp32 fallback (verified round 1)
        float* m2 = (float*)d_ws;
        float* x2 = m2 + N_;
        m2_kernel<<<N_ / 4, 256, 0, stream>>>(mem, m2);
        x2f_kernel<<<R_ / 256, 256, 0, stream>>>(phi, x2);
        dist_loss_kernel<<<R_ / TM, 256, 0, stream>>>(phi, mem, rp, m2, x2, out);
    }
}